// Round 11
// baseline (348.369 us; speedup 1.0000x reference)
//
#include <hip/hip_runtime.h>
#include <hip/hip_bf16.h>

typedef __bf16 bf16;
typedef __bf16 bf16x8 __attribute__((ext_vector_type(8)));
typedef __bf16 bf16x4 __attribute__((ext_vector_type(4)));
typedef float floatx4 __attribute__((ext_vector_type(4)));

typedef int  aint  __attribute__((may_alias));
typedef long along __attribute__((may_alias));

#define NPIX 4096
#define BATCH 4
#define LOG2E 1.4426950408889634f
// hT3 layout: [b][j>>5][c][j&31] bytes; 2048 B per j32-block, 262144 B per batch
#define HT_BATCH 262144
// DIAGNOSTIC: run the accumulation loops twice. num and den both double, so
// out = gamma*(2n)/(2d)+x is IDENTICAL; per-dispatch time doubles, pushing
// attn_kernel above the ~40.5us fill cutoff into the top-5 WITH counters.
// proj doubled likewise (idempotent re-stores). Remove REPS after reading.
#define REPS 2

__device__ inline bf16x8 zero8() {
    bf16x8 v;
    #pragma unroll
    for (int i = 0; i < 8; ++i) v[i] = (bf16)0.0f;
    return v;
}

// ---------------------------------------------------------------------------
// Kernel 1: projections via MFMA (identical math to R10, REPS x staging+compute)
// ---------------------------------------------------------------------------
__global__ __launch_bounds__(256) void proj_kernel(
    const float* __restrict__ x,
    const float* __restrict__ w_f, const float* __restrict__ b_f,
    const float* __restrict__ w_g, const float* __restrict__ b_g,
    const float* __restrict__ w_h, const float* __restrict__ b_h,
    bf16* __restrict__ fq, bf16* __restrict__ gq, unsigned char* __restrict__ hT)
{
    __shared__ bf16 xs[64 * 72];
    __shared__ bf16 wt[80 * 72];   // wt[n][c], n: 0-7 f, 8-15 g, 16-79 h
    __shared__ float bs[80];
    const int tid = threadIdx.x;
    const int p0 = blockIdx.x * 64;

    for (int rep = 0; rep < REPS; ++rep) {
    {   // stage x tile 64x64 f32 -> bf16 (coalesced float4)
        const float4* xg = (const float4*)(x + (long)p0 * 64);
        #pragma unroll
        for (int it = 0; it < 4; ++it) {
            int i4 = tid + it * 256;
            float4 v = xg[i4];
            int row = i4 >> 4, c4 = (i4 & 15) * 4;
            bf16x4 pk;
            pk[0] = (bf16)v.x; pk[1] = (bf16)v.y; pk[2] = (bf16)v.z; pk[3] = (bf16)v.w;
            *(bf16x4*)(&xs[row * 72 + c4]) = pk;
        }
    }
    for (int idx = tid; idx < 512; idx += 256) {
        int c = idx >> 3, n = idx & 7;
        wt[n * 72 + c]       = (bf16)w_f[idx];
        wt[(8 + n) * 72 + c] = (bf16)w_g[idx];
    }
    #pragma unroll
    for (int it = 0; it < 16; ++it) {
        int idx = tid + it * 256;               // 0..4095
        int c = idx >> 6, n = idx & 63;
        wt[(16 + n) * 72 + c] = (bf16)w_h[idx];
    }
    if (tid < 80)
        bs[tid] = (tid < 8) ? b_f[tid] : (tid < 16) ? b_g[tid - 8] : b_h[tid - 16];
    __syncthreads();

    const int wv = tid >> 6, lane = tid & 63;
    const int quad = lane >> 4, l15 = lane & 15;
    const int b = blockIdx.x >> 6;
    const int n0pix = (p0 & (NPIX - 1)) + wv * 16 + quad * 4;  // pixel-in-batch

    bf16x8 a0 = *(const bf16x8*)(&xs[(wv * 16 + l15) * 72 + quad * 8]);
    bf16x8 a1 = *(const bf16x8*)(&xs[(wv * 16 + l15) * 72 + 32 + quad * 8]);

    #pragma unroll
    for (int nt = 0; nt < 5; ++nt) {
        float bias = bs[nt * 16 + l15];
        floatx4 acc = {bias, bias, bias, bias};
        bf16x8 b0 = *(const bf16x8*)(&wt[(nt * 16 + l15) * 72 + quad * 8]);
        bf16x8 b1 = *(const bf16x8*)(&wt[(nt * 16 + l15) * 72 + 32 + quad * 8]);
        acc = __builtin_amdgcn_mfma_f32_16x16x32_bf16(a0, b0, acc, 0, 0, 0);
        acc = __builtin_amdgcn_mfma_f32_16x16x32_bf16(a1, b1, acc, 0, 0, 0);
        if (nt == 0) {
            #pragma unroll
            for (int r = 0; r < 4; ++r) {
                long P = (long)p0 + wv * 16 + quad * 4 + r;
                if (l15 < 8) fq[P * 8 + l15] = (bf16)acc[r];
                else         gq[P * 8 + (l15 - 8)] = (bf16)(acc[r] * LOG2E);
            }
        } else {
            int c = nt * 16 + l15 - 16;
            int pk = __builtin_amdgcn_cvt_pk_fp8_f32(acc[0], acc[1], 0, false);
            pk     = __builtin_amdgcn_cvt_pk_fp8_f32(acc[2], acc[3], pk, true);
            *(aint*)(hT + (long)b * HT_BATCH + (n0pix >> 5) * 2048
                     + c * 32 + (n0pix & 31)) = pk;
        }
    }
    __syncthreads();                            // between reps (benign)
    }
}

// ---------------------------------------------------------------------------
// Kernel 2: fp8 MFMA flash attention (R10 internals, REPS x the j-loop).
// num and den both scale by REPS -> out unchanged.
// ---------------------------------------------------------------------------
__global__ __launch_bounds__(512, 4) void attn_kernel(
    const bf16* __restrict__ fq, const bf16* __restrict__ gq,
    const unsigned char* __restrict__ hT, const float* __restrict__ x,
    const float* __restrict__ gamma_p, float* __restrict__ out)
{
    __shared__ float red[128 * 68];             // 34816 B: jq partial reduce
    const int tid  = threadIdx.x;
    const int wv   = tid >> 6, lane = tid & 63;
    const int quad = lane >> 4, l15 = lane & 15;
    const int igrp = wv & 1, jq = wv >> 1;
    const int b    = blockIdx.x >> 7, it = blockIdx.x & 127;
    const long rowbase = (long)b * NPIX + it * 32 + igrp * 16;  // wave's 16 i rows
    const int jbase = jq * 1024;

    // G fragment (bf16, pre-scaled by log2e): real k<8 in quad-0 lanes
    bf16x8 gfrag = zero8();
    if (lane < 16) gfrag = *(const bf16x8*)(gq + (rowbase + lane) * 8);

    const bf16* Fb = fq + ((long)b * NPIX + jbase) * 8;
    const unsigned char* Hb = hT + (long)b * HT_BATCH + (jbase >> 5) * 2048
                            + (l15 * 32 + quad * 8);   // per-lane part folded in

    floatx4 acc[5];                             // [0..3]=O channels, [4]=den
    #pragma unroll
    for (int nt = 0; nt < 5; ++nt) acc[nt] = (floatx4){0.f, 0.f, 0.f, 0.f};
    const along ones = 0x3838383838383838L;     // fp8 e4m3 1.0 x8

    // bpermute lane algebra (constant per lane)
    const int idx_lo = (((quad & 1) * 2) * 16 + l15) * 4;  // src lane*4 (m 0..3)
    const int idx_hi = idx_lo + 64;                        // +16 lanes  (m 4..7)
    const bool sel_b = (quad >> 1) != 0;                   // pk[2ks] vs pk[2ks+1]

    for (int rep = 0; rep < REPS; ++rep)
    for (int t = 0; t < 8; ++t) {
        // afrag loads FIRST (consumed first by S; vmcnt drains in issue order)
        bf16x8 af[8];
        #pragma unroll
        for (int j8 = 0; j8 < 8; ++j8) {
            af[j8] = zero8();
            if (lane < 16)
                af[j8] = *(const bf16x8*)(Fb + (t * 128 + j8 * 16 + l15) * 8);
        }
        // bfrag loads second (consumed last by PV; stay in flight through S)
        along bfr[16];
        #pragma unroll
        for (int ks = 0; ks < 4; ++ks)
            #pragma unroll
            for (int nt = 0; nt < 4; ++nt)
                bfr[ks * 4 + nt] = *(const along*)(Hb + (t * 4 + ks) * 2048 + nt * 512);

        // --- S^T = F·G^T (bf16), exp2, pack fp8 -> pk regs ---
        int pk[8];
        #pragma unroll
        for (int j8 = 0; j8 < 8; ++j8) {
            floatx4 s = __builtin_amdgcn_mfma_f32_16x16x32_bf16(
                af[j8], gfrag, (floatx4){0.f, 0.f, 0.f, 0.f}, 0, 0, 0);
            float e0 = __builtin_amdgcn_exp2f(s[0]);
            float e1 = __builtin_amdgcn_exp2f(s[1]);
            float e2 = __builtin_amdgcn_exp2f(s[2]);
            float e3 = __builtin_amdgcn_exp2f(s[3]);
            int p = __builtin_amdgcn_cvt_pk_fp8_f32(e0, e1, 0, false);
            pk[j8] = __builtin_amdgcn_cvt_pk_fp8_f32(e2, e3, p, true);
        }
        // --- in-register transpose (ds_bpermute) + PV (fp8 MFMA) ---
        #pragma unroll
        for (int ks = 0; ks < 4; ++ks) {
            int pa = pk[2 * ks], pb = pk[2 * ks + 1];
            int lo0 = __builtin_amdgcn_ds_bpermute(idx_lo, pa);
            int lo1 = __builtin_amdgcn_ds_bpermute(idx_lo, pb);
            int hi0 = __builtin_amdgcn_ds_bpermute(idx_hi, pa);
            int hi1 = __builtin_amdgcn_ds_bpermute(idx_hi, pb);
            unsigned lo = (unsigned)(sel_b ? lo1 : lo0);
            unsigned hi = (unsigned)(sel_b ? hi1 : hi0);
            along pfrag = (along)(((unsigned long)hi << 32) | lo);
            #pragma unroll
            for (int nt = 0; nt < 4; ++nt)
                acc[nt] = __builtin_amdgcn_mfma_f32_16x16x32_fp8_fp8(
                    pfrag, bfr[ks * 4 + nt], acc[nt], 0, 0, 0);
            acc[4] = __builtin_amdgcn_mfma_f32_16x16x32_fp8_fp8(pfrag, ones, acc[4], 0, 0, 0);
        }
    }

    // jq partials -> red[jq][32 local rows][68] (64 num + den at 64)
    {
        const int rb = (jq * 32 + igrp * 16 + quad * 4) * 68;
        #pragma unroll
        for (int nt = 0; nt < 4; ++nt)
            #pragma unroll
            for (int r = 0; r < 4; ++r)
                red[rb + r * 68 + nt * 16 + l15] = acc[nt][r];
        if (l15 == 0) {
            #pragma unroll
            for (int r = 0; r < 4; ++r)
                red[rb + r * 68 + 64] = acc[4][r];
        }
    }
    __syncthreads();

    // epilogue: 512 thr = 32 rows x 16 col-chunks of 4; fully coalesced
    {
        const int row = tid >> 4, c0 = (tid & 15) * 4;
        float4 n = {0.f, 0.f, 0.f, 0.f};
        float den = 0.f;
        #pragma unroll
        for (int q = 0; q < 4; ++q) {
            const float* rr = red + (q * 32 + row) * 68;
            float4 v = *(const float4*)(rr + c0);
            n.x += v.x; n.y += v.y; n.z += v.z; n.w += v.w;
            den += rr[64];
        }
        const float rd = gamma_p[0] / den;
        const long off = ((long)b * NPIX + it * 32 + row) * 64 + c0;
        float4 xv = *(const float4*)(x + off);
        float4 o;
        o.x = n.x * rd + xv.x; o.y = n.y * rd + xv.y;
        o.z = n.z * rd + xv.z; o.w = n.w * rd + xv.w;
        *(float4*)(out + off) = o;
    }
}

extern "C" void kernel_launch(void* const* d_in, const int* in_sizes, int n_in,
                              void* d_out, int out_size, void* d_ws, size_t ws_size,
                              hipStream_t stream) {
    const float* x     = (const float*)d_in[0];
    const float* w_f   = (const float*)d_in[1];
    const float* b_f   = (const float*)d_in[2];
    const float* w_g   = (const float*)d_in[3];
    const float* b_g   = (const float*)d_in[4];
    const float* w_h   = (const float*)d_in[5];
    const float* b_h   = (const float*)d_in[6];
    const float* gamma = (const float*)d_in[7];
    float* out = (float*)d_out;

    bf16* fq = (bf16*)d_ws;                                // 16384*8 bf16
    bf16* gq = fq + 16384 * 8;                             // 16384*8 bf16 (x log2e)
    unsigned char* hT = (unsigned char*)(gq + 16384 * 8);  // 4*262144 fp8 (tiled)

    proj_kernel<<<256, 256, 0, stream>>>(x, w_f, b_f, w_g, b_g, w_h, b_h, fq, gq, hT);
    attn_kernel<<<512, 512, 0, stream>>>(fq, gq, hT, x, gamma, out);
}

// Round 12
// 110.366 us; speedup vs baseline: 3.1565x; 3.1565x over previous
//
#include <hip/hip_runtime.h>
#include <hip/hip_bf16.h>

typedef __bf16 bf16;
typedef __bf16 bf16x8 __attribute__((ext_vector_type(8)));
typedef __bf16 bf16x4 __attribute__((ext_vector_type(4)));
typedef float floatx4 __attribute__((ext_vector_type(4)));

typedef int    aint    __attribute__((may_alias));
typedef long   along   __attribute__((may_alias));
typedef float4 afloat4 __attribute__((may_alias));

#define NPIX 4096
#define BATCH 4
#define LOG2E 1.4426950408889634f
// hT3 layout: [b][j>>5][c][j&31] bytes; 2048 B per j32-block, 262144 B per batch
#define HT_BATCH 262144

__device__ inline bf16x8 zero8() {
    bf16x8 v;
    #pragma unroll
    for (int i = 0; i < 8; ++i) v[i] = (bf16)0.0f;
    return v;
}

// ---------------------------------------------------------------------------
// Kernel 1: projections via MFMA (unchanged from R10 — verified).
//   fq [16384][8] bf16, gq [16384][8] bf16 (PRE-SCALED by log2e),
//   hT3 [4][128][64][32] fp8 e4m3 (PV-B-fragment-native layout).
// ---------------------------------------------------------------------------
__global__ __launch_bounds__(256) void proj_kernel(
    const float* __restrict__ x,
    const float* __restrict__ w_f, const float* __restrict__ b_f,
    const float* __restrict__ w_g, const float* __restrict__ b_g,
    const float* __restrict__ w_h, const float* __restrict__ b_h,
    bf16* __restrict__ fq, bf16* __restrict__ gq, unsigned char* __restrict__ hT)
{
    __shared__ bf16 xs[64 * 72];
    __shared__ bf16 wt[80 * 72];   // wt[n][c], n: 0-7 f, 8-15 g, 16-79 h
    __shared__ float bs[80];
    const int tid = threadIdx.x;
    const int p0 = blockIdx.x * 64;

    {   // stage x tile 64x64 f32 -> bf16 (coalesced float4)
        const float4* xg = (const float4*)(x + (long)p0 * 64);
        #pragma unroll
        for (int it = 0; it < 4; ++it) {
            int i4 = tid + it * 256;
            float4 v = xg[i4];
            int row = i4 >> 4, c4 = (i4 & 15) * 4;
            bf16x4 pk;
            pk[0] = (bf16)v.x; pk[1] = (bf16)v.y; pk[2] = (bf16)v.z; pk[3] = (bf16)v.w;
            *(bf16x4*)(&xs[row * 72 + c4]) = pk;
        }
    }
    for (int idx = tid; idx < 512; idx += 256) {
        int c = idx >> 3, n = idx & 7;
        wt[n * 72 + c]       = (bf16)w_f[idx];
        wt[(8 + n) * 72 + c] = (bf16)w_g[idx];
    }
    #pragma unroll
    for (int it = 0; it < 16; ++it) {
        int idx = tid + it * 256;               // 0..4095
        int c = idx >> 6, n = idx & 63;
        wt[(16 + n) * 72 + c] = (bf16)w_h[idx];
    }
    if (tid < 80)
        bs[tid] = (tid < 8) ? b_f[tid] : (tid < 16) ? b_g[tid - 8] : b_h[tid - 16];
    __syncthreads();

    const int wv = tid >> 6, lane = tid & 63;
    const int quad = lane >> 4, l15 = lane & 15;
    const int b = blockIdx.x >> 6;
    const int n0pix = (p0 & (NPIX - 1)) + wv * 16 + quad * 4;  // pixel-in-batch

    bf16x8 a0 = *(const bf16x8*)(&xs[(wv * 16 + l15) * 72 + quad * 8]);
    bf16x8 a1 = *(const bf16x8*)(&xs[(wv * 16 + l15) * 72 + 32 + quad * 8]);

    #pragma unroll
    for (int nt = 0; nt < 5; ++nt) {
        float bias = bs[nt * 16 + l15];
        floatx4 acc = {bias, bias, bias, bias};
        bf16x8 b0 = *(const bf16x8*)(&wt[(nt * 16 + l15) * 72 + quad * 8]);
        bf16x8 b1 = *(const bf16x8*)(&wt[(nt * 16 + l15) * 72 + 32 + quad * 8]);
        acc = __builtin_amdgcn_mfma_f32_16x16x32_bf16(a0, b0, acc, 0, 0, 0);
        acc = __builtin_amdgcn_mfma_f32_16x16x32_bf16(a1, b1, acc, 0, 0, 0);
        if (nt == 0) {
            #pragma unroll
            for (int r = 0; r < 4; ++r) {
                long P = (long)p0 + wv * 16 + quad * 4 + r;
                if (l15 < 8) fq[P * 8 + l15] = (bf16)acc[r];
                else         gq[P * 8 + (l15 - 8)] = (bf16)(acc[r] * LOG2E);
            }
        } else {
            int c = nt * 16 + l15 - 16;
            int pk = __builtin_amdgcn_cvt_pk_fp8_f32(acc[0], acc[1], 0, false);
            pk     = __builtin_amdgcn_cvt_pk_fp8_f32(acc[2], acc[3], pk, true);
            *(aint*)(hT + (long)b * HT_BATCH + (n0pix >> 5) * 2048
                     + c * 32 + (n0pix & 31)) = pk;
        }
    }
}

// ---------------------------------------------------------------------------
// Kernel 2: fp8 MFMA flash attention, LDS-STAGED with max tile sharing.
// R11 diagnosis: direct-global fragments caused 254 MB FETCH + 299 MB of
// dirty-poison writebacks (every L2 allocation evicts a 0xAA ws line).
// Fix: all 8 waves of a block share ONE j-range; each 10 KB tile (F 2KB +
// Ht 8KB) staged once, consumed 8x. Per-block global reads = 80 KB.
// Grid 512 = jh(4) x b(4) x it(32); block 512 = 8 waves x 16 i (128 i-rows).
// Double-buffered LDS, ONE barrier per tile (stage buf^1 writes and buf
// reads are disjoint; barrier closes the iteration). R10 core kept:
// bpermute in-register transpose, fp8 PV, ones-MFMA den.
// Cross-block jh partials -> reduce kernel (R6-verified).
// ---------------------------------------------------------------------------
__global__ __launch_bounds__(512, 4) void attn_kernel(
    const bf16* __restrict__ fq, const bf16* __restrict__ gq,
    const unsigned char* __restrict__ hT, float* __restrict__ partial)
{
    __shared__ char Ft[2][2048];                // F tile: 128 j x 16 B
    __shared__ char Ht[2][8192];                // Ht tile: 4 j32-blocks x 2048 B
    const int tid  = threadIdx.x;
    const int wv   = tid >> 6, lane = tid & 63;
    const int quad = lane >> 4, l15 = lane & 15;
    const int jh   = blockIdx.x >> 7;           // j quarter 0..3
    const int b    = (blockIdx.x >> 5) & 3;
    const int it   = blockIdx.x & 31;
    const long rowbase = (long)b * NPIX + it * 128 + wv * 16;  // wave's 16 i rows
    const int jbase = jh * 1024;

    // G fragment (bf16, pre-scaled by log2e): real k<8 in quad-0 lanes
    bf16x8 gfrag = zero8();
    if (lane < 16) gfrag = *(const bf16x8*)(gq + (rowbase + lane) * 8);

    const char* Fg = (const char*)(fq + ((long)b * NPIX + jbase) * 8);  // 2KB/tile
    const char* Hg = (const char*)hT + (long)b * HT_BATCH + (jbase >> 5) * 2048;

    floatx4 acc[5];                             // [0..3]=O channels, [4]=den
    #pragma unroll
    for (int nt = 0; nt < 5; ++nt) acc[nt] = (floatx4){0.f, 0.f, 0.f, 0.f};
    const along ones = 0x3838383838383838L;     // fp8 e4m3 1.0 x8

    // bpermute lane algebra (constant per lane)
    const int idx_lo = (((quad & 1) * 2) * 16 + l15) * 4;  // src lane*4 (m 0..3)
    const int idx_hi = idx_lo + 64;                        // +16 lanes  (m 4..7)
    const bool sel_b = (quad >> 1) != 0;                   // pk[2ks] vs pk[2ks+1]

    // prologue: stage tile 0 (H: 512 thr x 16 B; F: first 128 thr x 16 B)
    *(afloat4*)(Ht[0] + tid * 16) = *(const float4*)(Hg + tid * 16);
    if (tid < 128)
        *(afloat4*)(Ft[0] + tid * 16) = *(const float4*)(Fg + tid * 16);
    __syncthreads();

    for (int t = 0; t < 8; ++t) {
        const int buf = t & 1;
        // stage next tile into buf^1 (disjoint from this tile's reads)
        if (t < 7) {
            *(afloat4*)(Ht[buf ^ 1] + tid * 16) =
                *(const float4*)(Hg + (t + 1) * 8192 + tid * 16);
            if (tid < 128)
                *(afloat4*)(Ft[buf ^ 1] + tid * 16) =
                    *(const float4*)(Fg + (t + 1) * 2048 + tid * 16);
        }
        // --- S^T = F·G^T (bf16), exp2, pack fp8 -> pk regs ---
        int pk[8];
        #pragma unroll
        for (int j8 = 0; j8 < 8; ++j8) {
            bf16x8 afrag = zero8();
            if (lane < 16)
                afrag = *(const bf16x8*)(Ft[buf] + (j8 * 16 + l15) * 16);
            floatx4 s = __builtin_amdgcn_mfma_f32_16x16x32_bf16(
                afrag, gfrag, (floatx4){0.f, 0.f, 0.f, 0.f}, 0, 0, 0);
            float e0 = __builtin_amdgcn_exp2f(s[0]);
            float e1 = __builtin_amdgcn_exp2f(s[1]);
            float e2 = __builtin_amdgcn_exp2f(s[2]);
            float e3 = __builtin_amdgcn_exp2f(s[3]);
            int p = __builtin_amdgcn_cvt_pk_fp8_f32(e0, e1, 0, false);
            pk[j8] = __builtin_amdgcn_cvt_pk_fp8_f32(e2, e3, p, true);
        }
        // --- in-register transpose (ds_bpermute) + PV (fp8 MFMA) ---
        #pragma unroll
        for (int ks = 0; ks < 4; ++ks) {
            int pa = pk[2 * ks], pb = pk[2 * ks + 1];
            int lo0 = __builtin_amdgcn_ds_bpermute(idx_lo, pa);
            int lo1 = __builtin_amdgcn_ds_bpermute(idx_lo, pb);
            int hi0 = __builtin_amdgcn_ds_bpermute(idx_hi, pa);
            int hi1 = __builtin_amdgcn_ds_bpermute(idx_hi, pb);
            unsigned lo = (unsigned)(sel_b ? lo1 : lo0);
            unsigned hi = (unsigned)(sel_b ? hi1 : hi0);
            along pfrag = (along)(((unsigned long)hi << 32) | lo);
            #pragma unroll
            for (int nt = 0; nt < 4; ++nt) {
                along bfrag = *(const along*)(Ht[buf] + ks * 2048 + nt * 512
                                              + l15 * 32 + quad * 8);
                acc[nt] = __builtin_amdgcn_mfma_f32_16x16x32_fp8_fp8(
                    pfrag, bfrag, acc[nt], 0, 0, 0);
            }
            acc[4] = __builtin_amdgcn_mfma_f32_16x16x32_fp8_fp8(pfrag, ones, acc[4], 0, 0, 0);
        }
        __syncthreads();    // buf reads done + buf^1 staged; next t writes buf
    }

    // partials straight from regs: partial[jh][i][68] (64 num + den)
    float* pb = partial + ((long)jh * (BATCH * NPIX) + rowbase) * 68;
    #pragma unroll
    for (int nt = 0; nt < 4; ++nt)
        #pragma unroll
        for (int r = 0; r < 4; ++r)
            pb[(quad * 4 + r) * 68 + nt * 16 + l15] = acc[nt][r];
    if (l15 == 0) {
        #pragma unroll
        for (int r = 0; r < 4; ++r)
            pb[(quad * 4 + r) * 68 + 64] = acc[4][r];
    }
}

// ---------------------------------------------------------------------------
// Kernel 3: reduce 4 jh partials -> out = (gamma/den)*num + x  (R6-verified)
// 512 blocks x 256 thr; 8 threads per pixel row (8 channels each).
// ---------------------------------------------------------------------------
__global__ __launch_bounds__(256) void reduce_kernel(
    const float* __restrict__ partial, const float* __restrict__ x,
    const float* __restrict__ gamma_p, float* __restrict__ out)
{
    const int tid = threadIdx.x;
    const long i  = (long)blockIdx.x * 32 + (tid >> 3);
    const int c0  = (tid & 7) * 8;
    const float* p = partial + i * 68;
    float4 n0 = {0.f, 0.f, 0.f, 0.f}, n1 = {0.f, 0.f, 0.f, 0.f};
    float den = 0.f;
    #pragma unroll
    for (int js = 0; js < 4; ++js) {
        const float* pj = p + (long)js * (BATCH * NPIX) * 68;
        float4 a = *(const float4*)(pj + c0);
        float4 c = *(const float4*)(pj + c0 + 4);
        n0.x += a.x; n0.y += a.y; n0.z += a.z; n0.w += a.w;
        n1.x += c.x; n1.y += c.y; n1.z += c.z; n1.w += c.w;
        den += pj[64];
    }
    const float rd = gamma_p[0] / den;
    const float* xr = x + i * 64 + c0;
    float* orow = out + i * 64 + c0;
    float4 xa = *(const float4*)xr, xb = *(const float4*)(xr + 4);
    float4 oa, ob;
    oa.x = n0.x * rd + xa.x; oa.y = n0.y * rd + xa.y;
    oa.z = n0.z * rd + xa.z; oa.w = n0.w * rd + xa.w;
    ob.x = n1.x * rd + xb.x; ob.y = n1.y * rd + xb.y;
    ob.z = n1.z * rd + xb.z; ob.w = n1.w * rd + xb.w;
    *(float4*)orow = oa; *(float4*)(orow + 4) = ob;
}

extern "C" void kernel_launch(void* const* d_in, const int* in_sizes, int n_in,
                              void* d_out, int out_size, void* d_ws, size_t ws_size,
                              hipStream_t stream) {
    const float* x     = (const float*)d_in[0];
    const float* w_f   = (const float*)d_in[1];
    const float* b_f   = (const float*)d_in[2];
    const float* w_g   = (const float*)d_in[3];
    const float* b_g   = (const float*)d_in[4];
    const float* w_h   = (const float*)d_in[5];
    const float* b_h   = (const float*)d_in[6];
    const float* gamma = (const float*)d_in[7];
    float* out = (float*)d_out;

    bf16* fq = (bf16*)d_ws;                                // 16384*8 bf16
    bf16* gq = fq + 16384 * 8;                             // 16384*8 bf16 (x log2e)
    unsigned char* hT = (unsigned char*)(gq + 16384 * 8);  // 4*262144 fp8 (tiled)
    float* partial = (float*)(hT + (long)BATCH * HT_BATCH); // 4*16384*68 f32

    proj_kernel<<<256, 256, 0, stream>>>(x, w_f, b_f, w_g, b_g, w_h, b_h, fq, gq, hT);
    attn_kernel<<<512, 512, 0, stream>>>(fq, gq, hT, partial);
    reduce_kernel<<<512, 256, 0, stream>>>(partial, x, gamma, out);
}

// Round 13
// 97.002 us; speedup vs baseline: 3.5913x; 1.1378x over previous
//
#include <hip/hip_runtime.h>
#include <hip/hip_bf16.h>

typedef __bf16 bf16;
typedef __bf16 bf16x8 __attribute__((ext_vector_type(8)));
typedef __bf16 bf16x4 __attribute__((ext_vector_type(4)));
typedef float floatx4 __attribute__((ext_vector_type(4)));

typedef int  aint  __attribute__((may_alias));
typedef long along __attribute__((may_alias));

#define NPIX 4096
#define BATCH 4
#define LOG2E 1.4426950408889634f
// hT3 layout: [b][j>>5][c][j&31] bytes; 2048 B per j32-block, 262144 B per batch
#define HT_BATCH 262144

__device__ inline bf16x8 zero8() {
    bf16x8 v;
    #pragma unroll
    for (int i = 0; i < 8; ++i) v[i] = (bf16)0.0f;
    return v;
}

// ---------------------------------------------------------------------------
// Kernel 1: projections via MFMA (unchanged from R10 — verified).
//   fq [16384][8] bf16, gq [16384][8] bf16 (PRE-SCALED by log2e),
//   hT3 [4][128][64][32] fp8 e4m3 (PV-B-fragment-native layout).
// ---------------------------------------------------------------------------
__global__ __launch_bounds__(256) void proj_kernel(
    const float* __restrict__ x,
    const float* __restrict__ w_f, const float* __restrict__ b_f,
    const float* __restrict__ w_g, const float* __restrict__ b_g,
    const float* __restrict__ w_h, const float* __restrict__ b_h,
    bf16* __restrict__ fq, bf16* __restrict__ gq, unsigned char* __restrict__ hT)
{
    __shared__ bf16 xs[64 * 72];
    __shared__ bf16 wt[80 * 72];   // wt[n][c], n: 0-7 f, 8-15 g, 16-79 h
    __shared__ float bs[80];
    const int tid = threadIdx.x;
    const int p0 = blockIdx.x * 64;

    {   // stage x tile 64x64 f32 -> bf16 (coalesced float4)
        const float4* xg = (const float4*)(x + (long)p0 * 64);
        #pragma unroll
        for (int it = 0; it < 4; ++it) {
            int i4 = tid + it * 256;
            float4 v = xg[i4];
            int row = i4 >> 4, c4 = (i4 & 15) * 4;
            bf16x4 pk;
            pk[0] = (bf16)v.x; pk[1] = (bf16)v.y; pk[2] = (bf16)v.z; pk[3] = (bf16)v.w;
            *(bf16x4*)(&xs[row * 72 + c4]) = pk;
        }
    }
    for (int idx = tid; idx < 512; idx += 256) {
        int c = idx >> 3, n = idx & 7;
        wt[n * 72 + c]       = (bf16)w_f[idx];
        wt[(8 + n) * 72 + c] = (bf16)w_g[idx];
    }
    #pragma unroll
    for (int it = 0; it < 16; ++it) {
        int idx = tid + it * 256;               // 0..4095
        int c = idx >> 6, n = idx & 63;
        wt[(16 + n) * 72 + c] = (bf16)w_h[idx];
    }
    if (tid < 80)
        bs[tid] = (tid < 8) ? b_f[tid] : (tid < 16) ? b_g[tid - 8] : b_h[tid - 16];
    __syncthreads();

    const int wv = tid >> 6, lane = tid & 63;
    const int quad = lane >> 4, l15 = lane & 15;
    const int b = blockIdx.x >> 6;
    const int n0pix = (p0 & (NPIX - 1)) + wv * 16 + quad * 4;  // pixel-in-batch

    bf16x8 a0 = *(const bf16x8*)(&xs[(wv * 16 + l15) * 72 + quad * 8]);
    bf16x8 a1 = *(const bf16x8*)(&xs[(wv * 16 + l15) * 72 + 32 + quad * 8]);

    #pragma unroll
    for (int nt = 0; nt < 5; ++nt) {
        float bias = bs[nt * 16 + l15];
        floatx4 acc = {bias, bias, bias, bias};
        bf16x8 b0 = *(const bf16x8*)(&wt[(nt * 16 + l15) * 72 + quad * 8]);
        bf16x8 b1 = *(const bf16x8*)(&wt[(nt * 16 + l15) * 72 + 32 + quad * 8]);
        acc = __builtin_amdgcn_mfma_f32_16x16x32_bf16(a0, b0, acc, 0, 0, 0);
        acc = __builtin_amdgcn_mfma_f32_16x16x32_bf16(a1, b1, acc, 0, 0, 0);
        if (nt == 0) {
            #pragma unroll
            for (int r = 0; r < 4; ++r) {
                long P = (long)p0 + wv * 16 + quad * 4 + r;
                if (l15 < 8) fq[P * 8 + l15] = (bf16)acc[r];
                else         gq[P * 8 + (l15 - 8)] = (bf16)(acc[r] * LOG2E);
            }
        } else {
            int c = nt * 16 + l15 - 16;
            int pk = __builtin_amdgcn_cvt_pk_fp8_f32(acc[0], acc[1], 0, false);
            pk     = __builtin_amdgcn_cvt_pk_fp8_f32(acc[2], acc[3], pk, true);
            *(aint*)(hT + (long)b * HT_BATCH + (n0pix >> 5) * 2048
                     + c * 32 + (n0pix & 31)) = pk;
        }
    }
}

// ---------------------------------------------------------------------------
// Kernel 2: fp8 MFMA flash attention — R10 internals, ONE change: XCD-aware
// block swizzle. R11/R12 evidence: attn is L2-miss latency-bound (FETCH
// 254 MB vs 1.5 MB unique at REPS=2; MfmaUtil 4%, VALUBusy 7%) because the
// default (b,it) decode spreads all 4 batches' tiles (5 MB) across every
// XCD's 4 MB L2. Swizzle: dispatch round-robins blockIdx%8 over XCDs, so
//   xcd = blk&7, b = xcd>>1, it = (blk>>3) | ((xcd&1)<<6)
// pins each batch's 1.25 MB working set to one XCD pair -> L2-resident.
// Everything else bit-identical to R10 (in-block jq split, afrag-before-
// bfrag issue order, ds_bpermute in-register transpose, ones-MFMA den).
// ---------------------------------------------------------------------------
__global__ __launch_bounds__(512, 4) void attn_kernel(
    const bf16* __restrict__ fq, const bf16* __restrict__ gq,
    const unsigned char* __restrict__ hT, const float* __restrict__ x,
    const float* __restrict__ gamma_p, float* __restrict__ out)
{
    __shared__ float red[128 * 68];             // 34816 B: jq partial reduce
    const int tid  = threadIdx.x;
    const int wv   = tid >> 6, lane = tid & 63;
    const int quad = lane >> 4, l15 = lane & 15;
    const int igrp = wv & 1, jq = wv >> 1;
    // XCD-aware decode (pure permutation of block->work mapping)
    const int xcd = blockIdx.x & 7;
    const int b   = xcd >> 1;
    const int it  = ((blockIdx.x >> 3) & 63) | ((xcd & 1) << 6);   // 0..127
    const long rowbase = (long)b * NPIX + it * 32 + igrp * 16;  // wave's 16 i rows
    const int jbase = jq * 1024;

    // G fragment (bf16, pre-scaled by log2e): real k<8 in quad-0 lanes
    bf16x8 gfrag = zero8();
    if (lane < 16) gfrag = *(const bf16x8*)(gq + (rowbase + lane) * 8);

    const bf16* Fb = fq + ((long)b * NPIX + jbase) * 8;
    const unsigned char* Hb = hT + (long)b * HT_BATCH + (jbase >> 5) * 2048
                            + (l15 * 32 + quad * 8);   // per-lane part folded in

    floatx4 acc[5];                             // [0..3]=O channels, [4]=den
    #pragma unroll
    for (int nt = 0; nt < 5; ++nt) acc[nt] = (floatx4){0.f, 0.f, 0.f, 0.f};
    const along ones = 0x3838383838383838L;     // fp8 e4m3 1.0 x8

    // bpermute lane algebra (constant per lane)
    const int idx_lo = (((quad & 1) * 2) * 16 + l15) * 4;  // src lane*4 (m 0..3)
    const int idx_hi = idx_lo + 64;                        // +16 lanes  (m 4..7)
    const bool sel_b = (quad >> 1) != 0;                   // pk[2ks] vs pk[2ks+1]

    for (int t = 0; t < 8; ++t) {
        // afrag loads FIRST (consumed first by S; vmcnt drains in issue order)
        bf16x8 af[8];
        #pragma unroll
        for (int j8 = 0; j8 < 8; ++j8) {
            af[j8] = zero8();
            if (lane < 16)
                af[j8] = *(const bf16x8*)(Fb + (t * 128 + j8 * 16 + l15) * 8);
        }
        // bfrag loads second (consumed last by PV; stay in flight through S)
        along bfr[16];
        #pragma unroll
        for (int ks = 0; ks < 4; ++ks)
            #pragma unroll
            for (int nt = 0; nt < 4; ++nt)
                bfr[ks * 4 + nt] = *(const along*)(Hb + (t * 4 + ks) * 2048 + nt * 512);

        // --- S^T = F·G^T (bf16), exp2, pack fp8 -> pk regs ---
        int pk[8];
        #pragma unroll
        for (int j8 = 0; j8 < 8; ++j8) {
            floatx4 s = __builtin_amdgcn_mfma_f32_16x16x32_bf16(
                af[j8], gfrag, (floatx4){0.f, 0.f, 0.f, 0.f}, 0, 0, 0);
            float e0 = __builtin_amdgcn_exp2f(s[0]);
            float e1 = __builtin_amdgcn_exp2f(s[1]);
            float e2 = __builtin_amdgcn_exp2f(s[2]);
            float e3 = __builtin_amdgcn_exp2f(s[3]);
            int p = __builtin_amdgcn_cvt_pk_fp8_f32(e0, e1, 0, false);
            pk[j8] = __builtin_amdgcn_cvt_pk_fp8_f32(e2, e3, p, true);
        }
        // --- in-register transpose (ds_bpermute) + PV (fp8 MFMA) ---
        #pragma unroll
        for (int ks = 0; ks < 4; ++ks) {
            int pa = pk[2 * ks], pb = pk[2 * ks + 1];
            int lo0 = __builtin_amdgcn_ds_bpermute(idx_lo, pa);
            int lo1 = __builtin_amdgcn_ds_bpermute(idx_lo, pb);
            int hi0 = __builtin_amdgcn_ds_bpermute(idx_hi, pa);
            int hi1 = __builtin_amdgcn_ds_bpermute(idx_hi, pb);
            unsigned lo = (unsigned)(sel_b ? lo1 : lo0);
            unsigned hi = (unsigned)(sel_b ? hi1 : hi0);
            along pfrag = (along)(((unsigned long)hi << 32) | lo);
            #pragma unroll
            for (int nt = 0; nt < 4; ++nt)
                acc[nt] = __builtin_amdgcn_mfma_f32_16x16x32_fp8_fp8(
                    pfrag, bfr[ks * 4 + nt], acc[nt], 0, 0, 0);
            acc[4] = __builtin_amdgcn_mfma_f32_16x16x32_fp8_fp8(pfrag, ones, acc[4], 0, 0, 0);
        }
    }

    // jq partials -> red[jq][32 local rows][68] (64 num + den at 64)
    {
        const int rb = (jq * 32 + igrp * 16 + quad * 4) * 68;
        #pragma unroll
        for (int nt = 0; nt < 4; ++nt)
            #pragma unroll
            for (int r = 0; r < 4; ++r)
                red[rb + r * 68 + nt * 16 + l15] = acc[nt][r];
        if (l15 == 0) {
            #pragma unroll
            for (int r = 0; r < 4; ++r)
                red[rb + r * 68 + 64] = acc[4][r];
        }
    }
    __syncthreads();

    // epilogue: 512 thr = 32 rows x 16 col-chunks of 4; fully coalesced
    {
        const int row = tid >> 4, c0 = (tid & 15) * 4;
        float4 n = {0.f, 0.f, 0.f, 0.f};
        float den = 0.f;
        #pragma unroll
        for (int q = 0; q < 4; ++q) {
            const float* rr = red + (q * 32 + row) * 68;
            float4 v = *(const float4*)(rr + c0);
            n.x += v.x; n.y += v.y; n.z += v.z; n.w += v.w;
            den += rr[64];
        }
        const float rd = gamma_p[0] / den;
        const long off = ((long)b * NPIX + it * 32 + row) * 64 + c0;
        float4 xv = *(const float4*)(x + off);
        float4 o;
        o.x = n.x * rd + xv.x; o.y = n.y * rd + xv.y;
        o.z = n.z * rd + xv.z; o.w = n.w * rd + xv.w;
        *(float4*)(out + off) = o;
    }
}

extern "C" void kernel_launch(void* const* d_in, const int* in_sizes, int n_in,
                              void* d_out, int out_size, void* d_ws, size_t ws_size,
                              hipStream_t stream) {
    const float* x     = (const float*)d_in[0];
    const float* w_f   = (const float*)d_in[1];
    const float* b_f   = (const float*)d_in[2];
    const float* w_g   = (const float*)d_in[3];
    const float* b_g   = (const float*)d_in[4];
    const float* w_h   = (const float*)d_in[5];
    const float* b_h   = (const float*)d_in[6];
    const float* gamma = (const float*)d_in[7];
    float* out = (float*)d_out;

    bf16* fq = (bf16*)d_ws;                                // 16384*8 bf16
    bf16* gq = fq + 16384 * 8;                             // 16384*8 bf16 (x log2e)
    unsigned char* hT = (unsigned char*)(gq + 16384 * 8);  // 4*262144 fp8 (tiled)

    proj_kernel<<<256, 256, 0, stream>>>(x, w_f, b_f, w_g, b_g, w_h, b_h, fq, gq, hT);
    attn_kernel<<<512, 512, 0, stream>>>(fq, gq, hT, x, gamma, out);
}

// Round 14
// 95.567 us; speedup vs baseline: 3.6453x; 1.0150x over previous
//
#include <hip/hip_runtime.h>
#include <hip/hip_bf16.h>

typedef __bf16 bf16;
typedef __bf16 bf16x8 __attribute__((ext_vector_type(8)));
typedef __bf16 bf16x4 __attribute__((ext_vector_type(4)));
typedef float floatx4 __attribute__((ext_vector_type(4)));

typedef int  aint  __attribute__((may_alias));
typedef long along __attribute__((may_alias));

#define NPIX 4096
#define BATCH 4
#define LOG2E 1.4426950408889634f
// hT3 layout: [b][j>>5][c][j&31] bytes; 2048 B per j32-block, 262144 B per batch
#define HT_BATCH 262144

__device__ inline bf16x8 zero8() {
    bf16x8 v;
    #pragma unroll
    for (int i = 0; i < 8; ++i) v[i] = (bf16)0.0f;
    return v;
}

// ---------------------------------------------------------------------------
// Kernel 1: projections via MFMA (unchanged from R10/R13 — verified).
//   fq [16384][8] bf16, gq [16384][8] bf16 (PRE-SCALED by log2e),
//   hT3 [4][128][64][32] fp8 e4m3 (PV-B-fragment-native layout).
// ---------------------------------------------------------------------------
__global__ __launch_bounds__(256) void proj_kernel(
    const float* __restrict__ x,
    const float* __restrict__ w_f, const float* __restrict__ b_f,
    const float* __restrict__ w_g, const float* __restrict__ b_g,
    const float* __restrict__ w_h, const float* __restrict__ b_h,
    bf16* __restrict__ fq, bf16* __restrict__ gq, unsigned char* __restrict__ hT)
{
    __shared__ bf16 xs[64 * 72];
    __shared__ bf16 wt[80 * 72];   // wt[n][c], n: 0-7 f, 8-15 g, 16-79 h
    __shared__ float bs[80];
    const int tid = threadIdx.x;
    const int p0 = blockIdx.x * 64;

    {   // stage x tile 64x64 f32 -> bf16 (coalesced float4)
        const float4* xg = (const float4*)(x + (long)p0 * 64);
        #pragma unroll
        for (int it = 0; it < 4; ++it) {
            int i4 = tid + it * 256;
            float4 v = xg[i4];
            int row = i4 >> 4, c4 = (i4 & 15) * 4;
            bf16x4 pk;
            pk[0] = (bf16)v.x; pk[1] = (bf16)v.y; pk[2] = (bf16)v.z; pk[3] = (bf16)v.w;
            *(bf16x4*)(&xs[row * 72 + c4]) = pk;
        }
    }
    for (int idx = tid; idx < 512; idx += 256) {
        int c = idx >> 3, n = idx & 7;
        wt[n * 72 + c]       = (bf16)w_f[idx];
        wt[(8 + n) * 72 + c] = (bf16)w_g[idx];
    }
    #pragma unroll
    for (int it = 0; it < 16; ++it) {
        int idx = tid + it * 256;               // 0..4095
        int c = idx >> 6, n = idx & 63;
        wt[(16 + n) * 72 + c] = (bf16)w_h[idx];
    }
    if (tid < 80)
        bs[tid] = (tid < 8) ? b_f[tid] : (tid < 16) ? b_g[tid - 8] : b_h[tid - 16];
    __syncthreads();

    const int wv = tid >> 6, lane = tid & 63;
    const int quad = lane >> 4, l15 = lane & 15;
    const int b = blockIdx.x >> 6;
    const int n0pix = (p0 & (NPIX - 1)) + wv * 16 + quad * 4;  // pixel-in-batch

    bf16x8 a0 = *(const bf16x8*)(&xs[(wv * 16 + l15) * 72 + quad * 8]);
    bf16x8 a1 = *(const bf16x8*)(&xs[(wv * 16 + l15) * 72 + 32 + quad * 8]);

    #pragma unroll
    for (int nt = 0; nt < 5; ++nt) {
        float bias = bs[nt * 16 + l15];
        floatx4 acc = {bias, bias, bias, bias};
        bf16x8 b0 = *(const bf16x8*)(&wt[(nt * 16 + l15) * 72 + quad * 8]);
        bf16x8 b1 = *(const bf16x8*)(&wt[(nt * 16 + l15) * 72 + 32 + quad * 8]);
        acc = __builtin_amdgcn_mfma_f32_16x16x32_bf16(a0, b0, acc, 0, 0, 0);
        acc = __builtin_amdgcn_mfma_f32_16x16x32_bf16(a1, b1, acc, 0, 0, 0);
        if (nt == 0) {
            #pragma unroll
            for (int r = 0; r < 4; ++r) {
                long P = (long)p0 + wv * 16 + quad * 4 + r;
                if (l15 < 8) fq[P * 8 + l15] = (bf16)acc[r];
                else         gq[P * 8 + (l15 - 8)] = (bf16)(acc[r] * LOG2E);
            }
        } else {
            int c = nt * 16 + l15 - 16;
            int pk = __builtin_amdgcn_cvt_pk_fp8_f32(acc[0], acc[1], 0, false);
            pk     = __builtin_amdgcn_cvt_pk_fp8_f32(acc[2], acc[3], pk, true);
            *(aint*)(hT + (long)b * HT_BATCH + (n0pix >> 5) * 2048
                     + c * 32 + (n0pix & 31)) = pk;
        }
    }
}

// ---------------------------------------------------------------------------
// Kernel 2: fp8 MFMA flash attention — 2x OPERAND REUSE per wave.
// R13 diagnosis refined: attn is load-latency bound; loads-per-work is the
// lever. Wave now covers 32 i-rows (two G fragments): the SAME 8 afrag + 16
// bfrag loads per 128-j tile feed two S-phases and two PV-phases (loads per
// unit work halve). Block 256 = 4 waves sharing the same 32 i-rows, jq split
// 4 (1024 j each, 8 tiles); grid 512 = 4 blocks/CU, 4 waves/SIMD (unchanged
// occupancy). VGPR ~120 fits the (256,4) cap. Den via VALU adds on exact e
// (R4-verified numerics; VALU is idle). XCD swizzle, afrag-first issue
// order, ds_bpermute in-register transpose all kept from R13.
// ---------------------------------------------------------------------------
__global__ __launch_bounds__(256, 4) void attn_kernel(
    const bf16* __restrict__ fq, const bf16* __restrict__ gq,
    const unsigned char* __restrict__ hT, const float* __restrict__ x,
    const float* __restrict__ gamma_p, float* __restrict__ out)
{
    __shared__ float red[4 * 32 * 68];          // 34816 B: jq partial reduce
    const int tid  = threadIdx.x;
    const int wv   = tid >> 6, lane = tid & 63;
    const int quad = lane >> 4, l15 = lane & 15;
    const int jq   = wv;                        // each wave: one j-quarter
    // XCD-aware decode (R13-verified)
    const int xcd = blockIdx.x & 7;
    const int b   = xcd >> 1;
    const int it  = ((blockIdx.x >> 3) & 63) | ((xcd & 1) << 6);   // 0..127
    const long rowbase = (long)b * NPIX + it * 32;   // block's 32 i rows
    const int jbase = jq * 1024;

    // Two G fragments (bf16, pre-scaled by log2e): i-halves A (0-15), B (16-31)
    bf16x8 gfragA = zero8(), gfragB = zero8();
    if (lane < 16) {
        gfragA = *(const bf16x8*)(gq + (rowbase + lane) * 8);
        gfragB = *(const bf16x8*)(gq + (rowbase + 16 + lane) * 8);
    }

    const bf16* Fb = fq + ((long)b * NPIX + jbase) * 8;
    const unsigned char* Hb = hT + (long)b * HT_BATCH + (jbase >> 5) * 2048
                            + (l15 * 32 + quad * 8);   // per-lane part folded in

    floatx4 acc[8];                             // [h*4+nt]: O channels, halves A/B
    #pragma unroll
    for (int k = 0; k < 8; ++k) acc[k] = (floatx4){0.f, 0.f, 0.f, 0.f};
    float denA = 0.f, denB = 0.f;

    // bpermute lane algebra (constant per lane)
    const int idx_lo = (((quad & 1) * 2) * 16 + l15) * 4;  // src lane*4 (m 0..3)
    const int idx_hi = idx_lo + 64;                        // +16 lanes  (m 4..7)
    const bool sel_b = (quad >> 1) != 0;                   // pk[2ks] vs pk[2ks+1]

    for (int t = 0; t < 8; ++t) {
        // afrag loads FIRST (consumed first; vmcnt drains in issue order)
        bf16x8 af[8];
        #pragma unroll
        for (int j8 = 0; j8 < 8; ++j8) {
            af[j8] = zero8();
            if (lane < 16)
                af[j8] = *(const bf16x8*)(Fb + (t * 128 + j8 * 16 + l15) * 8);
        }
        // bfrag loads second (consumed last by PV; in flight through both S)
        along bfr[16];
        #pragma unroll
        for (int ks = 0; ks < 4; ++ks)
            #pragma unroll
            for (int nt = 0; nt < 4; ++nt)
                bfr[ks * 4 + nt] = *(const along*)(Hb + (t * 4 + ks) * 2048 + nt * 512);

        // --- S^T for BOTH i-halves from the same afrag; exp2; pack fp8 ---
        int pkA[8], pkB[8];
        #pragma unroll
        for (int j8 = 0; j8 < 8; ++j8) {
            floatx4 sA = __builtin_amdgcn_mfma_f32_16x16x32_bf16(
                af[j8], gfragA, (floatx4){0.f, 0.f, 0.f, 0.f}, 0, 0, 0);
            floatx4 sB = __builtin_amdgcn_mfma_f32_16x16x32_bf16(
                af[j8], gfragB, (floatx4){0.f, 0.f, 0.f, 0.f}, 0, 0, 0);
            float a0 = __builtin_amdgcn_exp2f(sA[0]);
            float a1 = __builtin_amdgcn_exp2f(sA[1]);
            float a2 = __builtin_amdgcn_exp2f(sA[2]);
            float a3 = __builtin_amdgcn_exp2f(sA[3]);
            float b0 = __builtin_amdgcn_exp2f(sB[0]);
            float b1 = __builtin_amdgcn_exp2f(sB[1]);
            float b2 = __builtin_amdgcn_exp2f(sB[2]);
            float b3 = __builtin_amdgcn_exp2f(sB[3]);
            denA += (a0 + a1) + (a2 + a3);
            denB += (b0 + b1) + (b2 + b3);
            int pa = __builtin_amdgcn_cvt_pk_fp8_f32(a0, a1, 0, false);
            pkA[j8] = __builtin_amdgcn_cvt_pk_fp8_f32(a2, a3, pa, true);
            int pb = __builtin_amdgcn_cvt_pk_fp8_f32(b0, b1, 0, false);
            pkB[j8] = __builtin_amdgcn_cvt_pk_fp8_f32(b2, b3, pb, true);
        }
        // --- in-register transpose (ds_bpermute) + PV, both halves,
        //     sharing the same bfr registers ---
        #pragma unroll
        for (int ks = 0; ks < 4; ++ks) {
            int loA0 = __builtin_amdgcn_ds_bpermute(idx_lo, pkA[2 * ks]);
            int loA1 = __builtin_amdgcn_ds_bpermute(idx_lo, pkA[2 * ks + 1]);
            int hiA0 = __builtin_amdgcn_ds_bpermute(idx_hi, pkA[2 * ks]);
            int hiA1 = __builtin_amdgcn_ds_bpermute(idx_hi, pkA[2 * ks + 1]);
            unsigned loA = (unsigned)(sel_b ? loA1 : loA0);
            unsigned hiA = (unsigned)(sel_b ? hiA1 : hiA0);
            along pfA = (along)(((unsigned long)hiA << 32) | loA);
            int loB0 = __builtin_amdgcn_ds_bpermute(idx_lo, pkB[2 * ks]);
            int loB1 = __builtin_amdgcn_ds_bpermute(idx_lo, pkB[2 * ks + 1]);
            int hiB0 = __builtin_amdgcn_ds_bpermute(idx_hi, pkB[2 * ks]);
            int hiB1 = __builtin_amdgcn_ds_bpermute(idx_hi, pkB[2 * ks + 1]);
            unsigned loB = (unsigned)(sel_b ? loB1 : loB0);
            unsigned hiB = (unsigned)(sel_b ? hiB1 : hiB0);
            along pfB = (along)(((unsigned long)hiB << 32) | loB);
            #pragma unroll
            for (int nt = 0; nt < 4; ++nt) {
                acc[nt]     = __builtin_amdgcn_mfma_f32_16x16x32_fp8_fp8(
                    pfA, bfr[ks * 4 + nt], acc[nt], 0, 0, 0);
                acc[4 + nt] = __builtin_amdgcn_mfma_f32_16x16x32_fp8_fp8(
                    pfB, bfr[ks * 4 + nt], acc[4 + nt], 0, 0, 0);
            }
        }
    }

    // den: reduce across quads (each quad held different j rows)
    denA += __shfl_xor(denA, 16);  denA += __shfl_xor(denA, 32);
    denB += __shfl_xor(denB, 16);  denB += __shfl_xor(denB, 32);

    // jq partials -> red[jq][32 rows][68] (64 num + den at 64)
    {
        const int rbA = (jq * 32 + quad * 4) * 68;        // half A rows 0-15
        const int rbB = (jq * 32 + 16 + quad * 4) * 68;   // half B rows 16-31
        #pragma unroll
        for (int nt = 0; nt < 4; ++nt)
            #pragma unroll
            for (int r = 0; r < 4; ++r) {
                red[rbA + r * 68 + nt * 16 + l15] = acc[nt][r];
                red[rbB + r * 68 + nt * 16 + l15] = acc[4 + nt][r];
            }
        if (quad == 0) {
            red[(jq * 32 + l15) * 68 + 64]      = denA;
            red[(jq * 32 + 16 + l15) * 68 + 64] = denB;
        }
    }
    __syncthreads();

    // epilogue: 256 thr = 32 rows x 8 col-chunks of 8; fully coalesced
    {
        const int row = tid >> 3, c0 = (tid & 7) * 8;
        float4 n0 = {0.f, 0.f, 0.f, 0.f}, n1 = {0.f, 0.f, 0.f, 0.f};
        float den = 0.f;
        #pragma unroll
        for (int q = 0; q < 4; ++q) {
            const float* rr = red + (q * 32 + row) * 68;
            float4 a = *(const float4*)(rr + c0);
            float4 c = *(const float4*)(rr + c0 + 4);
            n0.x += a.x; n0.y += a.y; n0.z += a.z; n0.w += a.w;
            n1.x += c.x; n1.y += c.y; n1.z += c.z; n1.w += c.w;
            den += rr[64];
        }
        const float rd = gamma_p[0] / den;
        const long off = (rowbase + row) * 64 + c0;
        float4 xa = *(const float4*)(x + off);
        float4 xb = *(const float4*)(x + off + 4);
        float4 oa, ob;
        oa.x = n0.x * rd + xa.x; oa.y = n0.y * rd + xa.y;
        oa.z = n0.z * rd + xa.z; oa.w = n0.w * rd + xa.w;
        ob.x = n1.x * rd + xb.x; ob.y = n1.y * rd + xb.y;
        ob.z = n1.z * rd + xb.z; ob.w = n1.w * rd + xb.w;
        *(float4*)(out + off) = oa;
        *(float4*)(out + off + 4) = ob;
    }
}

extern "C" void kernel_launch(void* const* d_in, const int* in_sizes, int n_in,
                              void* d_out, int out_size, void* d_ws, size_t ws_size,
                              hipStream_t stream) {
    const float* x     = (const float*)d_in[0];
    const float* w_f   = (const float*)d_in[1];
    const float* b_f   = (const float*)d_in[2];
    const float* w_g   = (const float*)d_in[3];
    const float* b_g   = (const float*)d_in[4];
    const float* w_h   = (const float*)d_in[5];
    const float* b_h   = (const float*)d_in[6];
    const float* gamma = (const float*)d_in[7];
    float* out = (float*)d_out;

    bf16* fq = (bf16*)d_ws;                                // 16384*8 bf16
    bf16* gq = fq + 16384 * 8;                             // 16384*8 bf16 (x log2e)
    unsigned char* hT = (unsigned char*)(gq + 16384 * 8);  // 4*262144 fp8 (tiled)

    proj_kernel<<<256, 256, 0, stream>>>(x, w_f, b_f, w_g, b_g, w_h, b_h, fq, gq, hT);
    attn_kernel<<<512, 256, 0, stream>>>(fq, gq, hT, x, gamma, out);
}